// Round 1
// baseline (7900.114 us; speedup 1.0000x reference)
//
#include <hip/hip_runtime.h>
#include <hip/hip_bf16.h>

typedef __attribute__((ext_vector_type(8))) short v8s;
typedef __attribute__((ext_vector_type(4))) float v4f;

static_assert(sizeof(v8s) == 16, "v8s must be 16B");

constexpr int BATCH = 256;
constexpr int SEQT  = 256;
constexpr int HID   = 512;
constexpr int NSLICES = 64;   // j-slices of 8 -> 64 * 8 = 512 hidden
constexpr int BGROUPS = 4;    // batch groups of 64

// ws layout (bytes):
//   flags0: [BGROUPS][SEQT] int            @ 0        (4096)
//   flags1: [BGROUPS][SEQT] int            @ 4096     (4096)
//   h_buf : [2][BATCH][HID] bf16           @ 8192     (524288)
//   h1    : [BATCH][SEQT][HID] bf16        @ 532480   (67108864)
//   mean  : [BATCH][HID] f32               @ 67641344 (524288)

__device__ inline short f2bf(float f) {
    __hip_bfloat16 h = __float2bfloat16(f);
    union { __hip_bfloat16 h; short s; } u;
    u.h = h;
    return u.s;
}

__device__ inline float sigmoidf_fast(float x) {
    return 1.0f / (1.0f + __expf(-x));
}

__device__ inline float tanhf_fast(float x) {
    // tanh(x) = 1 - 2/(e^{2x}+1); saturates correctly for large |x|
    return 1.0f - 2.0f / (__expf(2.0f * x) + 1.0f);
}

// One LSTM layer, persistent, batch-group-local step barrier.
// DIN = 64 (layer 0, input = xf fp32) or 512 (layer 1, input = xb bf16).
template<int DIN>
__global__ __launch_bounds__(256, 1)
void lstm_layer(const float* __restrict__ xf,
                const __hip_bfloat16* __restrict__ xb,
                const float* __restrict__ W_ih,   // [2048, DIN]
                const float* __restrict__ W_hh,   // [2048, 512]
                const float* __restrict__ bias,   // [2048]
                __hip_bfloat16* __restrict__ h_seq_out, // layer0: h1 out
                float* __restrict__ mean_out,           // layer1: mean over T
                __hip_bfloat16* __restrict__ h_buf,     // [2][BATCH][HID]
                int* __restrict__ flags)                // [BGROUPS][SEQT]
{
    constexpr int KBH = 16;        // 512 / 32 : recurrent K blocks
    constexpr int KBI = DIN / 32;  // input K blocks
    constexpr int KBT = KBH + KBI;

    __shared__ v8s ldsB[2 * KBT * 64];   // B-fragments, swizzled (<= 64 KB)

    const int tid   = threadIdx.x;
    const int lane  = tid & 63;
    const int wv    = tid >> 6;              // 0..3 : m-quarter
    const int slice = blockIdx.x & (NSLICES - 1);
    const int bg    = blockIdx.x >> 6;       // 0..3
    const int j0    = slice * 8;
    const int b0    = bg * 64;

    // ---- stage W_hh / W_ih slice into LDS in B-fragment order ----
    for (int idx = tid; idx < 2 * KBT * 64; idx += 256) {
        int tile = idx / (KBT * 64);
        int rem  = idx - tile * (KBT * 64);
        int kb   = rem >> 6;
        int ls   = rem & 63;
        int n    = tile * 16 + (ls & 15);    // 0..31 within wg's column slice
        int kh   = ls >> 4;
        int gate = n >> 3;
        int jj   = n & 7;
        int col  = gate * 512 + j0 + jj;     // global gate column
        int k    = kb * 32 + kh * 8;
        const float* src = (k < 512) ? (W_hh + col * 512 + k)
                                     : (W_ih + col * DIN + (k - 512));
        float4 f0 = ((const float4*)src)[0];
        float4 f1 = ((const float4*)src)[1];
        v8s b;
        b[0] = f2bf(f0.x); b[1] = f2bf(f0.y); b[2] = f2bf(f0.z); b[3] = f2bf(f0.w);
        b[4] = f2bf(f1.x); b[5] = f2bf(f1.y); b[6] = f2bf(f1.z); b[7] = f2bf(f1.w);
        ldsB[idx] = b;
    }
    __syncthreads();

    // per-lane constants
    const int m_a  = b0 + wv * 16 + (lane & 15);  // A-fragment row
    const int kh8  = (lane >> 4) * 8;             // A-fragment k offset
    const int jj   = lane & 7;
    const bool lowhalf = (lane & 8) == 0;
    const int rg   = lane >> 4;                   // C row group

    const float bi  = bias[0 * 512 + j0 + jj];
    const float bf_ = bias[1 * 512 + j0 + jj];
    const float bg_ = bias[2 * 512 + j0 + jj];
    const float bo  = bias[3 * 512 + j0 + jj];

    float c_r[4]  = {0.f, 0.f, 0.f, 0.f};
    float hsum[4] = {0.f, 0.f, 0.f, 0.f};

    int* flg = flags + bg * SEQT;

    for (int t = 0; t < SEQT; ++t) {
        if (t > 0) {
            if (tid == 0) {
                while (__hip_atomic_load(flg + (t - 1), __ATOMIC_ACQUIRE,
                                         __HIP_MEMORY_SCOPE_AGENT) < NSLICES) {
                    __builtin_amdgcn_s_sleep(1);
                }
            }
            __syncthreads();
        }

        v4f acc0 = {0.f, 0.f, 0.f, 0.f};
        v4f acc1 = {0.f, 0.f, 0.f, 0.f};

        // recurrent part: h_{t-1} @ W_hh^T   (skip at t=0, h0 = 0)
        if (t > 0) {
            const __hip_bfloat16* hb_read = h_buf + ((t + 1) & 1) * (BATCH * HID);
            const v8s* ap = (const v8s*)(hb_read + m_a * HID + kh8);
#pragma unroll
            for (int kb = 0; kb < KBH; ++kb) {
                v8s a   = ap[kb * 4];           // + kb*32 bf16
                v8s bb0 = ldsB[kb * 64 + lane];
                v8s bb1 = ldsB[(KBT + kb) * 64 + lane];
                acc0 = __builtin_amdgcn_mfma_f32_16x16x32_bf16(a, bb0, acc0, 0, 0, 0);
                acc1 = __builtin_amdgcn_mfma_f32_16x16x32_bf16(a, bb1, acc1, 0, 0, 0);
            }
        }

        // input part: x_t @ W_ih^T
#pragma unroll
        for (int kb = 0; kb < KBI; ++kb) {
            v8s a;
            if constexpr (DIN == 64) {
                const float* xp = xf + (m_a * SEQT + t) * 64 + kb * 32 + kh8;
                float4 f0 = ((const float4*)xp)[0];
                float4 f1 = ((const float4*)xp)[1];
                a[0] = f2bf(f0.x); a[1] = f2bf(f0.y); a[2] = f2bf(f0.z); a[3] = f2bf(f0.w);
                a[4] = f2bf(f1.x); a[5] = f2bf(f1.y); a[6] = f2bf(f1.z); a[7] = f2bf(f1.w);
            } else {
                a = *(const v8s*)(xb + (m_a * SEQT + t) * HID + kb * 32 + kh8);
            }
            v8s bb0 = ldsB[(KBH + kb) * 64 + lane];
            v8s bb1 = ldsB[(KBT + KBH + kb) * 64 + lane];
            acc0 = __builtin_amdgcn_mfma_f32_16x16x32_bf16(a, bb0, acc0, 0, 0, 0);
            acc1 = __builtin_amdgcn_mfma_f32_16x16x32_bf16(a, bb1, acc1, 0, 0, 0);
        }

        // ---- cell update: i/f and g/o live in partner lanes (lane ^ 8) ----
        v4f sw0, sw1;
#pragma unroll
        for (int r = 0; r < 4; ++r) {
            sw0[r] = __shfl_xor(acc0[r], 8, 64);
            sw1[r] = __shfl_xor(acc1[r], 8, 64);
        }

        float hval[4];
#pragma unroll
        for (int r = 0; r < 4; ++r) {
            float ig = (lowhalf ? acc0[r] : sw0[r]) + bi;
            float fg = (lowhalf ? sw0[r] : acc0[r]) + bf_;
            float gg = (lowhalf ? acc1[r] : sw1[r]) + bg_;
            float og = (lowhalf ? sw1[r] : acc1[r]) + bo;
            float iv = sigmoidf_fast(ig);
            float fv = sigmoidf_fast(fg);
            float gv = tanhf_fast(gg);
            float ov = sigmoidf_fast(og);
            float cv = fv * c_r[r] + iv * gv;
            c_r[r] = cv;
            hval[r] = ov * tanhf_fast(cv);
            hsum[r] += hval[r];
        }

        __hip_bfloat16* hb_write = h_buf + (t & 1) * (BATCH * HID);
        if (lowhalf) {
#pragma unroll
            for (int r = 0; r < 4; ++r) {
                int bcell = b0 + wv * 16 + rg * 4 + r;
                short hb = f2bf(hval[r]);
                *(short*)(hb_write + bcell * HID + j0 + jj) = hb;
                if constexpr (DIN == 64) {
                    *(short*)(h_seq_out + (bcell * SEQT + t) * HID + j0 + jj) = hb;
                }
            }
        }

        __syncthreads();   // drains vmcnt: all h stores issued before signal
        if (tid == 0) {
            __hip_atomic_fetch_add(flg + t, 1, __ATOMIC_RELEASE,
                                   __HIP_MEMORY_SCOPE_AGENT);
        }
    }

    if constexpr (DIN == 512) {
        if (lowhalf) {
#pragma unroll
            for (int r = 0; r < 4; ++r) {
                int bcell = b0 + wv * 16 + rg * 4 + r;
                mean_out[bcell * HID + j0 + jj] = hsum[r] * (1.0f / (float)SEQT);
            }
        }
    }
}

__global__ __launch_bounds__(256)
void head_kernel(const float* __restrict__ mean_h,
                 const float* __restrict__ W_sh, const float* __restrict__ b_sh,
                 const float* __restrict__ W_dir, const float* __restrict__ b_dir,
                 const float* __restrict__ W_mag, const float* __restrict__ b_mag,
                 float* __restrict__ out)
{
    __shared__ float mh[512];
    __shared__ float red[256];
    const int b = blockIdx.x;
    const int tid = threadIdx.x;

    mh[tid]       = mean_h[b * 512 + tid];
    mh[tid + 256] = mean_h[b * 512 + 256 + tid];
    __syncthreads();

    const float4* wrow = (const float4*)(W_sh + tid * 512);
    float dot = 0.f;
#pragma unroll 4
    for (int k4 = 0; k4 < 128; ++k4) {
        float4 w = wrow[k4];
        dot += w.x * mh[k4 * 4] + w.y * mh[k4 * 4 + 1]
             + w.z * mh[k4 * 4 + 2] + w.w * mh[k4 * 4 + 3];
    }
    float o = fmaxf(dot + b_sh[tid], 0.f) * 1.5f;

    red[tid] = o * W_dir[tid];
    __syncthreads();
    for (int s = 128; s > 0; s >>= 1) {
        if (tid < s) red[tid] += red[tid + s];
        __syncthreads();
    }
    if (tid == 0) out[b] = red[0] + b_dir[0];
    __syncthreads();

    red[tid] = o * W_mag[tid];
    __syncthreads();
    for (int s = 128; s > 0; s >>= 1) {
        if (tid < s) red[tid] += red[tid + s];
        __syncthreads();
    }
    if (tid == 0) out[256 + b] = red[0] + b_mag[0];
}

extern "C" void kernel_launch(void* const* d_in, const int* in_sizes, int n_in,
                              void* d_out, int out_size, void* d_ws, size_t ws_size,
                              hipStream_t stream) {
    const float* x    = (const float*)d_in[0];
    const float* Wih0 = (const float*)d_in[1];
    const float* Whh0 = (const float*)d_in[2];
    const float* b0   = (const float*)d_in[3];
    const float* Wih1 = (const float*)d_in[4];
    const float* Whh1 = (const float*)d_in[5];
    const float* b1   = (const float*)d_in[6];
    const float* Wsh  = (const float*)d_in[7];
    const float* bsh  = (const float*)d_in[8];
    const float* Wdir = (const float*)d_in[9];
    const float* bdir = (const float*)d_in[10];
    const float* Wmag = (const float*)d_in[11];
    const float* bmag = (const float*)d_in[12];

    char* ws = (char*)d_ws;
    int* flags0             = (int*)(ws);
    int* flags1             = (int*)(ws + 4096);
    __hip_bfloat16* h_buf   = (__hip_bfloat16*)(ws + 8192);
    __hip_bfloat16* h1      = (__hip_bfloat16*)(ws + 8192 + 524288);
    float* mean_h           = (float*)(ws + 8192 + 524288 + 67108864);

    hipMemsetAsync(flags0, 0, 8192, stream);  // zero both flag arrays

    lstm_layer<64><<<dim3(256), dim3(256), 0, stream>>>(
        x, nullptr, Wih0, Whh0, b0, h1, nullptr, h_buf, flags0);
    lstm_layer<512><<<dim3(256), dim3(256), 0, stream>>>(
        nullptr, h1, Wih1, Whh1, b1, nullptr, mean_h, h_buf, flags1);
    head_kernel<<<dim3(256), dim3(256), 0, stream>>>(
        mean_h, Wsh, bsh, Wdir, bdir, Wmag, bmag, (float*)d_out);
}

// Round 3
// 3045.571 us; speedup vs baseline: 2.5940x; 2.5940x over previous
//
#include <hip/hip_runtime.h>
#include <hip/hip_bf16.h>

typedef __attribute__((ext_vector_type(8))) short v8s;
typedef __attribute__((ext_vector_type(4))) float v4f;

static_assert(sizeof(v8s) == 16, "v8s must be 16B");

constexpr int BATCH = 256;
constexpr int SEQT  = 256;
constexpr int HID   = 512;
constexpr int NSLICES = 64;   // j-slices of 8 -> 64 * 8 = 512 hidden
constexpr int BGROUPS = 4;    // batch groups of 64

// ws layout (bytes):
//   flags0: [BGROUPS][NSLICES][4] int      @ 0        (4096)
//   flags1: [BGROUPS][NSLICES][4] int      @ 4096     (4096)
//   h_buf : [2][BATCH][HID] bf16           @ 8192     (524288)
//   h1    : [BATCH][SEQT][HID] bf16        @ 532480   (67108864)
//   mean  : [BATCH][HID] f32               @ 67641344 (524288)

__device__ inline short f2bf(float f) {
    __hip_bfloat16 h = __float2bfloat16(f);
    union { __hip_bfloat16 h; short s; } u;
    u.h = h;
    return u.s;
}

__device__ inline float sigmoidf_fast(float x) {
    return 1.0f / (1.0f + __expf(-x));
}

__device__ inline float tanhf_fast(float x) {
    return 1.0f - 2.0f / (__expf(2.0f * x) + 1.0f);
}

// 16 agent-coherent (sc1, L2-bypass) 16B loads of one h row-slice, all in
// flight together, then one vmcnt(0). Row stride within the block is 64 B
// (kb*32 bf16). Outputs are EARLY-CLOBBER (=&v): the address pair %16 must
// stay live across all 16 loads (missing & caused the round-2 fault).
__device__ inline void load_h16_sc1(const void* p, v8s a[16]) {
    asm volatile(
        "global_load_dwordx4 %0, %16, off sc1\n\t"
        "global_load_dwordx4 %1, %16, off offset:64 sc1\n\t"
        "global_load_dwordx4 %2, %16, off offset:128 sc1\n\t"
        "global_load_dwordx4 %3, %16, off offset:192 sc1\n\t"
        "global_load_dwordx4 %4, %16, off offset:256 sc1\n\t"
        "global_load_dwordx4 %5, %16, off offset:320 sc1\n\t"
        "global_load_dwordx4 %6, %16, off offset:384 sc1\n\t"
        "global_load_dwordx4 %7, %16, off offset:448 sc1\n\t"
        "global_load_dwordx4 %8, %16, off offset:512 sc1\n\t"
        "global_load_dwordx4 %9, %16, off offset:576 sc1\n\t"
        "global_load_dwordx4 %10, %16, off offset:640 sc1\n\t"
        "global_load_dwordx4 %11, %16, off offset:704 sc1\n\t"
        "global_load_dwordx4 %12, %16, off offset:768 sc1\n\t"
        "global_load_dwordx4 %13, %16, off offset:832 sc1\n\t"
        "global_load_dwordx4 %14, %16, off offset:896 sc1\n\t"
        "global_load_dwordx4 %15, %16, off offset:960 sc1\n\t"
        "s_waitcnt vmcnt(0)"
        : "=&v"(a[0]), "=&v"(a[1]), "=&v"(a[2]), "=&v"(a[3]),
          "=&v"(a[4]), "=&v"(a[5]), "=&v"(a[6]), "=&v"(a[7]),
          "=&v"(a[8]), "=&v"(a[9]), "=&v"(a[10]), "=&v"(a[11]),
          "=&v"(a[12]), "=&v"(a[13]), "=&v"(a[14]), "=&v"(a[15])
        : "v"(p)
        : "memory");
}

__device__ inline void store_bf16_sc1(void* p, int v) {
    asm volatile("global_store_short %0, %1, off sc1"
                 :: "v"(p), "v"(v) : "memory");
}

// One LSTM layer, persistent, batch-group-local step handshake via
// per-slice flags (plain sc1 stores, parallel polling — no RMW, no
// acquire/release cache flushes).
// DIN = 64 (layer 0, input = xf fp32) or 512 (layer 1, input = xb bf16).
template<int DIN>
__global__ __launch_bounds__(256, 1)
void lstm_layer(const float* __restrict__ xf,
                const __hip_bfloat16* __restrict__ xb,
                const float* __restrict__ W_ih,   // [2048, DIN]
                const float* __restrict__ W_hh,   // [2048, 512]
                const float* __restrict__ bias,   // [2048]
                __hip_bfloat16* __restrict__ h_seq_out, // layer0: h1 out
                float* __restrict__ mean_out,           // layer1: mean over T
                __hip_bfloat16* __restrict__ h_buf,     // [2][BATCH][HID]
                int* __restrict__ flags)                // [BGROUPS][NSLICES][4]
{
    constexpr int KBH = 16;        // 512 / 32 : recurrent K blocks
    constexpr int KBI = DIN / 32;  // input K blocks
    constexpr int KBT = KBH + KBI;

    __shared__ v8s ldsB[2 * KBT * 64];   // B-fragments, swizzled (<= 64 KB)

    const int tid   = threadIdx.x;
    const int lane  = tid & 63;
    const int wv    = tid >> 6;              // 0..3 : m-quarter
    const int slice = blockIdx.x & (NSLICES - 1);
    const int bg    = blockIdx.x >> 6;       // 0..3
    const int j0    = slice * 8;
    const int b0    = bg * 64;

    // ---- stage W_hh / W_ih slice into LDS in B-fragment order ----
    for (int idx = tid; idx < 2 * KBT * 64; idx += 256) {
        int tile = idx / (KBT * 64);
        int rem  = idx - tile * (KBT * 64);
        int kb   = rem >> 6;
        int ls   = rem & 63;
        int n    = tile * 16 + (ls & 15);    // 0..31 within wg's column slice
        int kh   = ls >> 4;
        int gate = n >> 3;
        int jj   = n & 7;
        int col  = gate * 512 + j0 + jj;     // global gate column
        int k    = kb * 32 + kh * 8;
        const float* src = (k < 512) ? (W_hh + col * 512 + k)
                                     : (W_ih + col * DIN + (k - 512));
        float4 f0 = ((const float4*)src)[0];
        float4 f1 = ((const float4*)src)[1];
        v8s b;
        b[0] = f2bf(f0.x); b[1] = f2bf(f0.y); b[2] = f2bf(f0.z); b[3] = f2bf(f0.w);
        b[4] = f2bf(f1.x); b[5] = f2bf(f1.y); b[6] = f2bf(f1.z); b[7] = f2bf(f1.w);
        ldsB[idx] = b;
    }
    __syncthreads();

    // per-lane constants
    const int m_a  = b0 + wv * 16 + (lane & 15);  // A-fragment row
    const int kh8  = (lane >> 4) * 8;             // A-fragment k offset
    const int jj   = lane & 7;
    const bool lowhalf = (lane & 8) == 0;
    const int rg   = lane >> 4;                   // C row group

    const float bi  = bias[0 * 512 + j0 + jj];
    const float bf_ = bias[1 * 512 + j0 + jj];
    const float bg_ = bias[2 * 512 + j0 + jj];
    const float bo  = bias[3 * 512 + j0 + jj];

    float c_r[4]  = {0.f, 0.f, 0.f, 0.f};
    float hsum[4] = {0.f, 0.f, 0.f, 0.f};

    int* flgbase  = flags + bg * (NSLICES * 4);
    int* myflag   = flgbase + slice * 4;
    int* pollflag = flgbase + lane * 4;   // wave 0: one flag per lane

    for (int t = 0; t < SEQT; ++t) {
        v4f acc0 = {0.f, 0.f, 0.f, 0.f};
        v4f acc1 = {0.f, 0.f, 0.f, 0.f};

        // ---- input part first: independent of h_{t-1}, runs during skew ----
#pragma unroll
        for (int kb = 0; kb < KBI; ++kb) {
            v8s a;
            if constexpr (DIN == 64) {
                const float* xp = xf + (m_a * SEQT + t) * 64 + kb * 32 + kh8;
                float4 f0 = ((const float4*)xp)[0];
                float4 f1 = ((const float4*)xp)[1];
                a[0] = f2bf(f0.x); a[1] = f2bf(f0.y); a[2] = f2bf(f0.z); a[3] = f2bf(f0.w);
                a[4] = f2bf(f1.x); a[5] = f2bf(f1.y); a[6] = f2bf(f1.z); a[7] = f2bf(f1.w);
            } else {
                a = *(const v8s*)(xb + (m_a * SEQT + t) * HID + kb * 32 + kh8);
            }
            v8s bb0 = ldsB[(KBH + kb) * 64 + lane];
            v8s bb1 = ldsB[(KBT + KBH + kb) * 64 + lane];
            acc0 = __builtin_amdgcn_mfma_f32_16x16x32_bf16(a, bb0, acc0, 0, 0, 0);
            acc1 = __builtin_amdgcn_mfma_f32_16x16x32_bf16(a, bb1, acc1, 0, 0, 0);
        }

        // ---- wait: all 64 slices of this bg have finished step t-1 ----
        if (t > 0) {
            if (wv == 0) {
                while (__hip_atomic_load(pollflag, __ATOMIC_RELAXED,
                                         __HIP_MEMORY_SCOPE_AGENT) < t) {
                    __builtin_amdgcn_s_sleep(4);
                }
            }
            __syncthreads();

            // recurrent part: h_{t-1} @ W_hh^T
            const __hip_bfloat16* hb_read = h_buf + ((t + 1) & 1) * (BATCH * HID);
            v8s a[16];
            load_h16_sc1(hb_read + m_a * HID + kh8, a);
#pragma unroll
            for (int kb = 0; kb < KBH; ++kb) {
                acc0 = __builtin_amdgcn_mfma_f32_16x16x32_bf16(a[kb], ldsB[kb * 64 + lane], acc0, 0, 0, 0);
                acc1 = __builtin_amdgcn_mfma_f32_16x16x32_bf16(a[kb], ldsB[(KBT + kb) * 64 + lane], acc1, 0, 0, 0);
            }
        }

        // ---- cell update: i/f and g/o live in partner lanes (lane ^ 8) ----
        v4f sw0, sw1;
#pragma unroll
        for (int r = 0; r < 4; ++r) {
            sw0[r] = __shfl_xor(acc0[r], 8, 64);
            sw1[r] = __shfl_xor(acc1[r], 8, 64);
        }

        float hval[4];
#pragma unroll
        for (int r = 0; r < 4; ++r) {
            float ig = (lowhalf ? acc0[r] : sw0[r]) + bi;
            float fg = (lowhalf ? sw0[r] : acc0[r]) + bf_;
            float gg = (lowhalf ? acc1[r] : sw1[r]) + bg_;
            float og = (lowhalf ? sw1[r] : acc1[r]) + bo;
            float iv = sigmoidf_fast(ig);
            float fv = sigmoidf_fast(fg);
            float gv = tanhf_fast(gg);
            float ov = sigmoidf_fast(og);
            float cv = fv * c_r[r] + iv * gv;
            c_r[r] = cv;
            hval[r] = ov * tanhf_fast(cv);
            hsum[r] += hval[r];
        }

        __hip_bfloat16* hb_write = h_buf + (t & 1) * (BATCH * HID);
        if (lowhalf) {
#pragma unroll
            for (int r = 0; r < 4; ++r) {
                int bcell = b0 + wv * 16 + rg * 4 + r;
                short hb = f2bf(hval[r]);
                store_bf16_sc1(hb_write + bcell * HID + j0 + jj, (int)(unsigned short)hb);
                if constexpr (DIN == 64) {
                    *(short*)(h_seq_out + (bcell * SEQT + t) * HID + j0 + jj) = hb;
                }
            }
        }

        // drain our stores to the coherence point, then signal our slice done
        asm volatile("s_waitcnt vmcnt(0)" ::: "memory");
        __syncthreads();
        if (tid == 0) {
            __hip_atomic_store(myflag, t + 1, __ATOMIC_RELAXED,
                               __HIP_MEMORY_SCOPE_AGENT);
        }
    }

    if constexpr (DIN == 512) {
        if (lowhalf) {
#pragma unroll
            for (int r = 0; r < 4; ++r) {
                int bcell = b0 + wv * 16 + rg * 4 + r;
                mean_out[bcell * HID + j0 + jj] = hsum[r] * (1.0f / (float)SEQT);
            }
        }
    }
}

__global__ __launch_bounds__(256)
void head_kernel(const float* __restrict__ mean_h,
                 const float* __restrict__ W_sh, const float* __restrict__ b_sh,
                 const float* __restrict__ W_dir, const float* __restrict__ b_dir,
                 const float* __restrict__ W_mag, const float* __restrict__ b_mag,
                 float* __restrict__ out)
{
    __shared__ float mh[512];
    __shared__ float red[256];
    const int b = blockIdx.x;
    const int tid = threadIdx.x;

    mh[tid]       = mean_h[b * 512 + tid];
    mh[tid + 256] = mean_h[b * 512 + 256 + tid];
    __syncthreads();

    const float4* wrow = (const float4*)(W_sh + tid * 512);
    float dot = 0.f;
#pragma unroll 4
    for (int k4 = 0; k4 < 128; ++k4) {
        float4 w = wrow[k4];
        dot += w.x * mh[k4 * 4] + w.y * mh[k4 * 4 + 1]
             + w.z * mh[k4 * 4 + 2] + w.w * mh[k4 * 4 + 3];
    }
    float o = fmaxf(dot + b_sh[tid], 0.f) * 1.5f;

    red[tid] = o * W_dir[tid];
    __syncthreads();
    for (int s = 128; s > 0; s >>= 1) {
        if (tid < s) red[tid] += red[tid + s];
        __syncthreads();
    }
    if (tid == 0) out[b] = red[0] + b_dir[0];
    __syncthreads();

    red[tid] = o * W_mag[tid];
    __syncthreads();
    for (int s = 128; s > 0; s >>= 1) {
        if (tid < s) red[tid] += red[tid + s];
        __syncthreads();
    }
    if (tid == 0) out[256 + b] = red[0] + b_mag[0];
}

extern "C" void kernel_launch(void* const* d_in, const int* in_sizes, int n_in,
                              void* d_out, int out_size, void* d_ws, size_t ws_size,
                              hipStream_t stream) {
    const float* x    = (const float*)d_in[0];
    const float* Wih0 = (const float*)d_in[1];
    const float* Whh0 = (const float*)d_in[2];
    const float* b0   = (const float*)d_in[3];
    const float* Wih1 = (const float*)d_in[4];
    const float* Whh1 = (const float*)d_in[5];
    const float* b1   = (const float*)d_in[6];
    const float* Wsh  = (const float*)d_in[7];
    const float* bsh  = (const float*)d_in[8];
    const float* Wdir = (const float*)d_in[9];
    const float* bdir = (const float*)d_in[10];
    const float* Wmag = (const float*)d_in[11];
    const float* bmag = (const float*)d_in[12];

    char* ws = (char*)d_ws;
    int* flags0             = (int*)(ws);
    int* flags1             = (int*)(ws + 4096);
    __hip_bfloat16* h_buf   = (__hip_bfloat16*)(ws + 8192);
    __hip_bfloat16* h1      = (__hip_bfloat16*)(ws + 8192 + 524288);
    float* mean_h           = (float*)(ws + 8192 + 524288 + 67108864);

    hipMemsetAsync(flags0, 0, 8192, stream);  // zero both flag arrays

    lstm_layer<64><<<dim3(256), dim3(256), 0, stream>>>(
        x, nullptr, Wih0, Whh0, b0, h1, nullptr, h_buf, flags0);
    lstm_layer<512><<<dim3(256), dim3(256), 0, stream>>>(
        nullptr, h1, Wih1, Whh1, b1, nullptr, mean_h, h_buf, flags1);
    head_kernel<<<dim3(256), dim3(256), 0, stream>>>(
        mean_h, Wsh, bsh, Wdir, bdir, Wmag, bmag, (float*)d_out);
}

// Round 5
// 2947.865 us; speedup vs baseline: 2.6799x; 1.0331x over previous
//
#include <hip/hip_runtime.h>
#include <hip/hip_bf16.h>

typedef __attribute__((ext_vector_type(8))) short v8s;
typedef __attribute__((ext_vector_type(4))) float v4f;

static_assert(sizeof(v8s) == 16, "v8s must be 16B");

constexpr int BATCH = 256;
constexpr int SEQT  = 256;
constexpr int HID   = 512;
constexpr int NSLICES = 64;   // j-slices of 8 -> 64 * 8 = 512 hidden
constexpr int KBH  = 16;      // 512/32 recurrent K blocks
constexpr int KBI0 = 2;       // layer0 input K blocks (D=64)
constexpr int KBT0 = KBH + KBI0;   // 18
constexpr int KBI1 = 16;      // layer1 input K blocks (D=512)
constexpr int KBT1 = KBH + KBI1;   // 32

// ws layout (bytes) — NO h1seq (L1 input == L0's hbuf0 ring, same bytes):
//   flags : [4][NSLICES][4] int            @ 0        (4096)
//   hbuf0 : [2][BATCH][HID] bf16           @ 8192     (524288)
//   hbuf1 : [2][BATCH][HID] bf16           @ 532480   (524288)
//   mean  : [BATCH][HID] f32               @ 1056768  (524288)
// total ~1.6 MB (round-4 bug: h1seq size was understated 2x and overlapped
// mean -> cross-bg race. h1seq removed entirely.)

__device__ inline short f2bf(float f) {
    __hip_bfloat16 h = __float2bfloat16(f);
    union { __hip_bfloat16 h; short s; } u;
    u.h = h;
    return u.s;
}

__device__ inline float sigmoidf_fast(float x) {
    return 1.0f / (1.0f + __expf(-x));
}

__device__ inline float tanhf_fast(float x) {
    return 1.0f - 2.0f / (__expf(2.0f * x) + 1.0f);
}

// Agent-coherent (sc1) tile-row load: 16 v8s fragments (256 B/lane) as
// 32 relaxed agent-scope u64 atomic loads -> global_load_dwordx2 sc1,
// compiler-tracked so independent loads stay in flight across compute.
__device__ inline void load_row_sc1(const void* rowp, v8s f[16]) {
    const unsigned long long* p = (const unsigned long long*)rowp;
#pragma unroll
    for (int k = 0; k < 16; ++k) {
        union { unsigned long long q[2]; v8s v; } u;
        u.q[0] = __hip_atomic_load(p + k * 8,     __ATOMIC_RELAXED,
                                   __HIP_MEMORY_SCOPE_AGENT);
        u.q[1] = __hip_atomic_load(p + k * 8 + 1, __ATOMIC_RELAXED,
                                   __HIP_MEMORY_SCOPE_AGENT);
        f[k] = u.v;
    }
}

__device__ inline void store_bf16_sc1(void* p, int v) {
    asm volatile("global_store_short %0, %1, off sc1"
                 :: "v"(p), "v"(v) : "memory");
}

// gates in acc0 (i|f) and acc1 (g|o), partner data in lane^8
__device__ inline void cell_update(const v4f& acc0, const v4f& acc1,
                                   float bi, float bf_, float bg_, float bo,
                                   bool lowhalf, float c[4], float hval[4]) {
    v4f sw0, sw1;
#pragma unroll
    for (int r = 0; r < 4; ++r) {
        sw0[r] = __shfl_xor(acc0[r], 8, 64);
        sw1[r] = __shfl_xor(acc1[r], 8, 64);
    }
#pragma unroll
    for (int r = 0; r < 4; ++r) {
        float ig = (lowhalf ? acc0[r] : sw0[r]) + bi;
        float fg = (lowhalf ? sw0[r] : acc0[r]) + bf_;
        float gg = (lowhalf ? acc1[r] : sw1[r]) + bg_;
        float og = (lowhalf ? sw1[r] : acc1[r]) + bo;
        float iv = sigmoidf_fast(ig);
        float fv = sigmoidf_fast(fg);
        float gv = tanhf_fast(gg);
        float ov = sigmoidf_fast(og);
        float cv = fv * c[r] + iv * gv;
        c[r] = cv;
        hval[r] = ov * tanhf_fast(cv);
    }
}

// Fused 2-layer LSTM: wg (bg, slice) owns 32 gate cols of BOTH layers.
// Iteration t: layer0 step t, layer1 step t-1, ONE flag handshake.
// L1's input (layer-0 h at step t-1) comes from the SAME hbuf0 ring row
// that L0's recurrent path loads — one sc1 load feeds both.
__global__ __launch_bounds__(256, 1)
void lstm_fused(const float* __restrict__ x,
                const float* __restrict__ Wih0, const float* __restrict__ Whh0,
                const float* __restrict__ bias0,
                const float* __restrict__ Wih1, const float* __restrict__ Whh1,
                const float* __restrict__ bias1,
                float* __restrict__ mean_out,          // [B][H]
                __hip_bfloat16* __restrict__ hbuf0,    // [2][B][H]
                __hip_bfloat16* __restrict__ hbuf1,    // [2][B][H]
                int* __restrict__ flags)               // [4][NSLICES][4]
{
    __shared__ v8s ldsB0[2 * KBT0 * 64];   // 36,864 B
    __shared__ v8s ldsB1[2 * KBT1 * 64];   // 65,536 B  (total ~100 KB)

    const int tid   = threadIdx.x;
    const int lane  = tid & 63;
    const int wv    = tid >> 6;
    const int slice = blockIdx.x & (NSLICES - 1);
    const int bg    = blockIdx.x >> 6;
    const int j0    = slice * 8;
    const int b0    = bg * 64;

    // ---- stage both layers' weight slices into LDS (B-fragment order) ----
    for (int idx = tid; idx < 2 * KBT0 * 64; idx += 256) {
        int tile = idx / (KBT0 * 64);
        int rem  = idx - tile * (KBT0 * 64);
        int kb   = rem >> 6;
        int ls   = rem & 63;
        int n    = tile * 16 + (ls & 15);
        int kh   = ls >> 4;
        int col  = (n >> 3) * 512 + j0 + (n & 7);
        int k    = kb * 32 + kh * 8;
        const float* src = (k < 512) ? (Whh0 + col * 512 + k)
                                     : (Wih0 + col * 64 + (k - 512));
        float4 f0 = ((const float4*)src)[0];
        float4 f1 = ((const float4*)src)[1];
        v8s b;
        b[0] = f2bf(f0.x); b[1] = f2bf(f0.y); b[2] = f2bf(f0.z); b[3] = f2bf(f0.w);
        b[4] = f2bf(f1.x); b[5] = f2bf(f1.y); b[6] = f2bf(f1.z); b[7] = f2bf(f1.w);
        ldsB0[idx] = b;
    }
    for (int idx = tid; idx < 2 * KBT1 * 64; idx += 256) {
        int tile = idx / (KBT1 * 64);
        int rem  = idx - tile * (KBT1 * 64);
        int kb   = rem >> 6;
        int ls   = rem & 63;
        int n    = tile * 16 + (ls & 15);
        int kh   = ls >> 4;
        int col  = (n >> 3) * 512 + j0 + (n & 7);
        int k    = kb * 32 + kh * 8;
        const float* src = (k < 512) ? (Whh1 + col * 512 + k)
                                     : (Wih1 + col * 512 + (k - 512));
        float4 f0 = ((const float4*)src)[0];
        float4 f1 = ((const float4*)src)[1];
        v8s b;
        b[0] = f2bf(f0.x); b[1] = f2bf(f0.y); b[2] = f2bf(f0.z); b[3] = f2bf(f0.w);
        b[4] = f2bf(f1.x); b[5] = f2bf(f1.y); b[6] = f2bf(f1.z); b[7] = f2bf(f1.w);
        ldsB1[idx] = b;
    }
    __syncthreads();

    // per-lane constants
    const int m_a  = b0 + wv * 16 + (lane & 15);  // A-fragment row (batch)
    const int kh8  = (lane >> 4) * 8;             // A-fragment k offset
    const int jj   = lane & 7;
    const bool lowhalf = (lane & 8) == 0;
    const int rg   = lane >> 4;

    const float bi0 = bias0[0 * 512 + j0 + jj];
    const float bf0 = bias0[1 * 512 + j0 + jj];
    const float bg0 = bias0[2 * 512 + j0 + jj];
    const float bo0 = bias0[3 * 512 + j0 + jj];
    const float bi1 = bias1[0 * 512 + j0 + jj];
    const float bf1 = bias1[1 * 512 + j0 + jj];
    const float bg1 = bias1[2 * 512 + j0 + jj];
    const float bo1 = bias1[3 * 512 + j0 + jj];

    float c0[4]   = {0.f, 0.f, 0.f, 0.f};
    float c1[4]   = {0.f, 0.f, 0.f, 0.f};
    float hsum[4] = {0.f, 0.f, 0.f, 0.f};

    int* flgbase  = flags + bg * (NSLICES * 4);
    int* myflag   = flgbase + slice * 4;
    int* pollflag = flgbase + lane * 4;

    for (int t = 0; t <= SEQT; ++t) {
        const bool doL0  = (t < SEQT);
        const bool doL0r = doL0 && (t > 0);
        const int  s     = t - 1;
        const bool doL1  = (t > 0);
        const bool doL1r = doL1 && (s > 0);

        // ---- L0 x-projection: independent of any flag, do before wait ----
        v4f a00 = {0.f, 0.f, 0.f, 0.f};
        v4f a01 = {0.f, 0.f, 0.f, 0.f};
        if (doL0) {
#pragma unroll
            for (int kb = 0; kb < KBI0; ++kb) {
                const float* xp = x + (m_a * SEQT + t) * 64 + kb * 32 + kh8;
                float4 f0 = ((const float4*)xp)[0];
                float4 f1 = ((const float4*)xp)[1];
                v8s a;
                a[0] = f2bf(f0.x); a[1] = f2bf(f0.y); a[2] = f2bf(f0.z); a[3] = f2bf(f0.w);
                a[4] = f2bf(f1.x); a[5] = f2bf(f1.y); a[6] = f2bf(f1.z); a[7] = f2bf(f1.w);
                a00 = __builtin_amdgcn_mfma_f32_16x16x32_bf16(a, ldsB0[(KBH + kb) * 64 + lane], a00, 0, 0, 0);
                a01 = __builtin_amdgcn_mfma_f32_16x16x32_bf16(a, ldsB0[(KBT0 + KBH + kb) * 64 + lane], a01, 0, 0, 0);
            }
        }

        // ---- single merged wait: peers completed iteration t-1 ----
        if (t > 0) {
            if (wv == 0) {
                while (__hip_atomic_load(pollflag, __ATOMIC_RELAXED,
                                         __HIP_MEMORY_SCOPE_AGENT) < t) {
                    __builtin_amdgcn_s_sleep(2);
                }
            }
            __syncthreads();
        }

        // ---- ONE load of layer-0 h at step t-1: feeds L0-recurrent AND
        //      L1-input. Plus L1's own recurrent h at step s-1.
        v8s fA0[16], fA2[16];
        if (t > 0) {
            const __hip_bfloat16* hb0r = hbuf0 + ((t + 1) & 1) * (BATCH * HID);
            load_row_sc1(hb0r + m_a * HID + kh8, fA0);
        }
        if (doL1r) {
            const __hip_bfloat16* hb1r = hbuf1 + ((s + 1) & 1) * (BATCH * HID);
            load_row_sc1(hb1r + m_a * HID + kh8, fA2);
        }

        // ---- L0 recurrent MFMAs + cell + store ----
        if (doL0) {
            if (doL0r) {
#pragma unroll
                for (int kb = 0; kb < KBH; ++kb) {
                    a00 = __builtin_amdgcn_mfma_f32_16x16x32_bf16(fA0[kb], ldsB0[kb * 64 + lane], a00, 0, 0, 0);
                    a01 = __builtin_amdgcn_mfma_f32_16x16x32_bf16(fA0[kb], ldsB0[(KBT0 + kb) * 64 + lane], a01, 0, 0, 0);
                }
            }
            float hval[4];
            cell_update(a00, a01, bi0, bf0, bg0, bo0, lowhalf, c0, hval);
            __hip_bfloat16* hb0w = hbuf0 + (t & 1) * (BATCH * HID);
            if (lowhalf) {
#pragma unroll
                for (int r = 0; r < 4; ++r) {
                    int bcell = b0 + wv * 16 + rg * 4 + r;
                    short hb = f2bf(hval[r]);
                    store_bf16_sc1(hb0w + bcell * HID + j0 + jj, (int)(unsigned short)hb);
                }
            }
        }

        // ---- L1 step s: x-part from fA0 (= layer-0 h step s), recurrent fA2 ----
        if (doL1) {
            v4f a10 = {0.f, 0.f, 0.f, 0.f};
            v4f a11 = {0.f, 0.f, 0.f, 0.f};
#pragma unroll
            for (int kb = 0; kb < KBI1; ++kb) {
                a10 = __builtin_amdgcn_mfma_f32_16x16x32_bf16(fA0[kb], ldsB1[(KBH + kb) * 64 + lane], a10, 0, 0, 0);
                a11 = __builtin_amdgcn_mfma_f32_16x16x32_bf16(fA0[kb], ldsB1[(KBT1 + KBH + kb) * 64 + lane], a11, 0, 0, 0);
            }
            if (doL1r) {
#pragma unroll
                for (int kb = 0; kb < KBH; ++kb) {
                    a10 = __builtin_amdgcn_mfma_f32_16x16x32_bf16(fA2[kb], ldsB1[kb * 64 + lane], a10, 0, 0, 0);
                    a11 = __builtin_amdgcn_mfma_f32_16x16x32_bf16(fA2[kb], ldsB1[(KBT1 + kb) * 64 + lane], a11, 0, 0, 0);
                }
            }
            float hval[4];
            cell_update(a10, a11, bi1, bf1, bg1, bo1, lowhalf, c1, hval);
#pragma unroll
            for (int r = 0; r < 4; ++r) hsum[r] += hval[r];
            __hip_bfloat16* hb1w = hbuf1 + (s & 1) * (BATCH * HID);
            if (lowhalf) {
#pragma unroll
                for (int r = 0; r < 4; ++r) {
                    int bcell = b0 + wv * 16 + rg * 4 + r;
                    short hb = f2bf(hval[r]);
                    store_bf16_sc1(hb1w + bcell * HID + j0 + jj, (int)(unsigned short)hb);
                }
            }
        }

        // ---- merged drain + signal ----
        asm volatile("s_waitcnt vmcnt(0)" ::: "memory");
        __syncthreads();
        if (tid == 0) {
            __hip_atomic_store(myflag, t + 1, __ATOMIC_RELAXED,
                               __HIP_MEMORY_SCOPE_AGENT);
        }
    }

    if (lowhalf) {
#pragma unroll
        for (int r = 0; r < 4; ++r) {
            int bcell = b0 + wv * 16 + rg * 4 + r;
            mean_out[bcell * HID + j0 + jj] = hsum[r] * (1.0f / (float)SEQT);
        }
    }
}

__global__ __launch_bounds__(256)
void head_kernel(const float* __restrict__ mean_h,
                 const float* __restrict__ W_sh, const float* __restrict__ b_sh,
                 const float* __restrict__ W_dir, const float* __restrict__ b_dir,
                 const float* __restrict__ W_mag, const float* __restrict__ b_mag,
                 float* __restrict__ out)
{
    __shared__ float mh[512];
    __shared__ float red[256];
    const int b = blockIdx.x;
    const int tid = threadIdx.x;

    mh[tid]       = mean_h[b * 512 + tid];
    mh[tid + 256] = mean_h[b * 512 + 256 + tid];
    __syncthreads();

    const float4* wrow = (const float4*)(W_sh + tid * 512);
    float dot = 0.f;
#pragma unroll 4
    for (int k4 = 0; k4 < 128; ++k4) {
        float4 w = wrow[k4];
        dot += w.x * mh[k4 * 4] + w.y * mh[k4 * 4 + 1]
             + w.z * mh[k4 * 4 + 2] + w.w * mh[k4 * 4 + 3];
    }
    float o = fmaxf(dot + b_sh[tid], 0.f) * 1.5f;

    red[tid] = o * W_dir[tid];
    __syncthreads();
    for (int s = 128; s > 0; s >>= 1) {
        if (tid < s) red[tid] += red[tid + s];
        __syncthreads();
    }
    if (tid == 0) out[b] = red[0] + b_dir[0];
    __syncthreads();

    red[tid] = o * W_mag[tid];
    __syncthreads();
    for (int s = 128; s > 0; s >>= 1) {
        if (tid < s) red[tid] += red[tid + s];
        __syncthreads();
    }
    if (tid == 0) out[256 + b] = red[0] + b_mag[0];
}

extern "C" void kernel_launch(void* const* d_in, const int* in_sizes, int n_in,
                              void* d_out, int out_size, void* d_ws, size_t ws_size,
                              hipStream_t stream) {
    const float* x    = (const float*)d_in[0];
    const float* Wih0 = (const float*)d_in[1];
    const float* Whh0 = (const float*)d_in[2];
    const float* b0   = (const float*)d_in[3];
    const float* Wih1 = (const float*)d_in[4];
    const float* Whh1 = (const float*)d_in[5];
    const float* b1   = (const float*)d_in[6];
    const float* Wsh  = (const float*)d_in[7];
    const float* bsh  = (const float*)d_in[8];
    const float* Wdir = (const float*)d_in[9];
    const float* bdir = (const float*)d_in[10];
    const float* Wmag = (const float*)d_in[11];
    const float* bmag = (const float*)d_in[12];

    char* ws = (char*)d_ws;
    int* flags              = (int*)(ws);
    __hip_bfloat16* hbuf0   = (__hip_bfloat16*)(ws + 8192);
    __hip_bfloat16* hbuf1   = (__hip_bfloat16*)(ws + 8192 + 524288);
    float* mean_h           = (float*)(ws + 8192 + 2 * 524288);

    hipMemsetAsync(flags, 0, 4096, stream);

    lstm_fused<<<dim3(256), dim3(256), 0, stream>>>(
        x, Wih0, Whh0, b0, Wih1, Whh1, b1,
        mean_h, hbuf0, hbuf1, flags);
    head_kernel<<<dim3(256), dim3(256), 0, stream>>>(
        mean_h, Wsh, bsh, Wdir, bdir, Wmag, bmag, (float*)d_out);
}

// Round 6
// 2374.773 us; speedup vs baseline: 3.3267x; 1.2413x over previous
//
#include <hip/hip_runtime.h>
#include <hip/hip_bf16.h>

typedef __attribute__((ext_vector_type(8))) short v8s;
typedef __attribute__((ext_vector_type(4))) float v4f;

static_assert(sizeof(v8s) == 16, "v8s must be 16B");

constexpr int BATCH = 256;
constexpr int SEQT  = 256;
constexpr int HID   = 512;
constexpr int NSLICES = 64;   // j-slices of 8 -> 64 * 8 = 512 hidden
constexpr int KBH  = 16;      // 512/32 recurrent K blocks
constexpr int KBI0 = 2;       // layer0 input K blocks (D=64)
constexpr int KBT0 = KBH + KBI0;   // 18
constexpr int KBI1 = 16;      // layer1 input K blocks (D=512)
constexpr int KBT1 = KBH + KBI1;   // 32

// ws layout (bytes):
//   flags : [4][2][NSLICES][4] int         @ 0        (8192)
//   hbuf0 : [2][BATCH][HID] bf16           @ 8192     (524288)
//   hbuf1 : [2][BATCH][HID] bf16           @ 532480   (524288)
//   mean  : [BATCH][HID] f32               @ 1056768  (524288)

__device__ inline short f2bf(float f) {
    __hip_bfloat16 h = __float2bfloat16(f);
    union { __hip_bfloat16 h; short s; } u;
    u.h = h;
    return u.s;
}

__device__ inline float sigmoidf_fast(float x) {
    return 1.0f / (1.0f + __expf(-x));
}

__device__ inline float tanhf_fast(float x) {
    return 1.0f - 2.0f / (__expf(2.0f * x) + 1.0f);
}

// 16 agent-coherent (sc1) 16-B loads of one h row-slice in ONE asm block:
// all 16 in flight, one vmcnt(0). Row-major fragments coalesce 4 lanes per
// 64-B line per instruction (kc groups are +16B within a line). This is the
// round-3-proven structure; round-5's u64 atomic pairs doubled request count
// and killed intra-line merging — reverted.
__device__ inline void load_h16_sc1(const void* p, v8s a[16]) {
    asm volatile(
        "global_load_dwordx4 %0, %16, off sc1\n\t"
        "global_load_dwordx4 %1, %16, off offset:64 sc1\n\t"
        "global_load_dwordx4 %2, %16, off offset:128 sc1\n\t"
        "global_load_dwordx4 %3, %16, off offset:192 sc1\n\t"
        "global_load_dwordx4 %4, %16, off offset:256 sc1\n\t"
        "global_load_dwordx4 %5, %16, off offset:320 sc1\n\t"
        "global_load_dwordx4 %6, %16, off offset:384 sc1\n\t"
        "global_load_dwordx4 %7, %16, off offset:448 sc1\n\t"
        "global_load_dwordx4 %8, %16, off offset:512 sc1\n\t"
        "global_load_dwordx4 %9, %16, off offset:576 sc1\n\t"
        "global_load_dwordx4 %10, %16, off offset:640 sc1\n\t"
        "global_load_dwordx4 %11, %16, off offset:704 sc1\n\t"
        "global_load_dwordx4 %12, %16, off offset:768 sc1\n\t"
        "global_load_dwordx4 %13, %16, off offset:832 sc1\n\t"
        "global_load_dwordx4 %14, %16, off offset:896 sc1\n\t"
        "global_load_dwordx4 %15, %16, off offset:960 sc1\n\t"
        "s_waitcnt vmcnt(0)"
        : "=&v"(a[0]), "=&v"(a[1]), "=&v"(a[2]), "=&v"(a[3]),
          "=&v"(a[4]), "=&v"(a[5]), "=&v"(a[6]), "=&v"(a[7]),
          "=&v"(a[8]), "=&v"(a[9]), "=&v"(a[10]), "=&v"(a[11]),
          "=&v"(a[12]), "=&v"(a[13]), "=&v"(a[14]), "=&v"(a[15])
        : "v"(p)
        : "memory");
}

__device__ inline void store_bf16_sc1(void* p, int v) {
    asm volatile("global_store_short %0, %1, off sc1"
                 :: "v"(p), "v"(v) : "memory");
}

// gates in acc0 (i|f) and acc1 (g|o), partner data in lane^8
__device__ inline void cell_update(const v4f& acc0, const v4f& acc1,
                                   float bi, float bf_, float bg_, float bo,
                                   bool lowhalf, float c[4], float hval[4]) {
    v4f sw0, sw1;
#pragma unroll
    for (int r = 0; r < 4; ++r) {
        sw0[r] = __shfl_xor(acc0[r], 8, 64);
        sw1[r] = __shfl_xor(acc1[r], 8, 64);
    }
#pragma unroll
    for (int r = 0; r < 4; ++r) {
        float ig = (lowhalf ? acc0[r] : sw0[r]) + bi;
        float fg = (lowhalf ? sw0[r] : acc0[r]) + bf_;
        float gg = (lowhalf ? acc1[r] : sw1[r]) + bg_;
        float og = (lowhalf ? sw1[r] : acc1[r]) + bo;
        float iv = sigmoidf_fast(ig);
        float fv = sigmoidf_fast(fg);
        float gv = tanhf_fast(gg);
        float ov = sigmoidf_fast(og);
        float cv = fv * c[r] + iv * gv;
        c[r] = cv;
        hval[r] = ov * tanhf_fast(cv);
    }
}

// Fused 2-layer LSTM with SPLIT per-layer flags:
//   flagL0(t) signaled right after L0's h store drains (early in iteration),
//   flagL1(t) at iteration end. Consumers: fA0 needs peers' flagL0(t-1);
//   fA2 needs peers' flagL1(t-1) (signaled one L1-phase earlier -> ~free).
// Critical cycle per iteration = handshake + L0 work only.
__global__ __launch_bounds__(256, 1)
void lstm_fused(const float* __restrict__ x,
                const float* __restrict__ Wih0, const float* __restrict__ Whh0,
                const float* __restrict__ bias0,
                const float* __restrict__ Wih1, const float* __restrict__ Whh1,
                const float* __restrict__ bias1,
                float* __restrict__ mean_out,          // [B][H]
                __hip_bfloat16* __restrict__ hbuf0,    // [2][B][H]
                __hip_bfloat16* __restrict__ hbuf1,    // [2][B][H]
                int* __restrict__ flags)               // [4][2][NSLICES][4]
{
    __shared__ v8s ldsB0[2 * KBT0 * 64];   // 36,864 B
    __shared__ v8s ldsB1[2 * KBT1 * 64];   // 65,536 B  (total ~100 KB)

    const int tid   = threadIdx.x;
    const int lane  = tid & 63;
    const int wv    = tid >> 6;
    const int slice = blockIdx.x & (NSLICES - 1);
    const int bg    = blockIdx.x >> 6;
    const int j0    = slice * 8;
    const int b0    = bg * 64;

    // ---- stage both layers' weight slices into LDS (B-fragment order) ----
    for (int idx = tid; idx < 2 * KBT0 * 64; idx += 256) {
        int tile = idx / (KBT0 * 64);
        int rem  = idx - tile * (KBT0 * 64);
        int kb   = rem >> 6;
        int ls   = rem & 63;
        int n    = tile * 16 + (ls & 15);
        int kh   = ls >> 4;
        int col  = (n >> 3) * 512 + j0 + (n & 7);
        int k    = kb * 32 + kh * 8;
        const float* src = (k < 512) ? (Whh0 + col * 512 + k)
                                     : (Wih0 + col * 64 + (k - 512));
        float4 f0 = ((const float4*)src)[0];
        float4 f1 = ((const float4*)src)[1];
        v8s b;
        b[0] = f2bf(f0.x); b[1] = f2bf(f0.y); b[2] = f2bf(f0.z); b[3] = f2bf(f0.w);
        b[4] = f2bf(f1.x); b[5] = f2bf(f1.y); b[6] = f2bf(f1.z); b[7] = f2bf(f1.w);
        ldsB0[idx] = b;
    }
    for (int idx = tid; idx < 2 * KBT1 * 64; idx += 256) {
        int tile = idx / (KBT1 * 64);
        int rem  = idx - tile * (KBT1 * 64);
        int kb   = rem >> 6;
        int ls   = rem & 63;
        int n    = tile * 16 + (ls & 15);
        int kh   = ls >> 4;
        int col  = (n >> 3) * 512 + j0 + (n & 7);
        int k    = kb * 32 + kh * 8;
        const float* src = (k < 512) ? (Whh1 + col * 512 + k)
                                     : (Wih1 + col * 512 + (k - 512));
        float4 f0 = ((const float4*)src)[0];
        float4 f1 = ((const float4*)src)[1];
        v8s b;
        b[0] = f2bf(f0.x); b[1] = f2bf(f0.y); b[2] = f2bf(f0.z); b[3] = f2bf(f0.w);
        b[4] = f2bf(f1.x); b[5] = f2bf(f1.y); b[6] = f2bf(f1.z); b[7] = f2bf(f1.w);
        ldsB1[idx] = b;
    }
    __syncthreads();

    // per-lane constants
    const int m_a  = b0 + wv * 16 + (lane & 15);  // A-fragment row (batch)
    const int kh8  = (lane >> 4) * 8;             // A-fragment k offset
    const int jj   = lane & 7;
    const bool lowhalf = (lane & 8) == 0;
    const int rg   = lane >> 4;

    const float bi0 = bias0[0 * 512 + j0 + jj];
    const float bf0 = bias0[1 * 512 + j0 + jj];
    const float bg0 = bias0[2 * 512 + j0 + jj];
    const float bo0 = bias0[3 * 512 + j0 + jj];
    const float bi1 = bias1[0 * 512 + j0 + jj];
    const float bf1 = bias1[1 * 512 + j0 + jj];
    const float bg1 = bias1[2 * 512 + j0 + jj];
    const float bo1 = bias1[3 * 512 + j0 + jj];

    float c0[4]   = {0.f, 0.f, 0.f, 0.f};
    float c1[4]   = {0.f, 0.f, 0.f, 0.f};
    float hsum[4] = {0.f, 0.f, 0.f, 0.f};

    int* flgL0 = flags + bg * (2 * NSLICES * 4);
    int* flgL1 = flgL0 + NSLICES * 4;
    int* myflagL0   = flgL0 + slice * 4;
    int* myflagL1   = flgL1 + slice * 4;
    int* pollflagL0 = flgL0 + lane * 4;
    int* pollflagL1 = flgL1 + lane * 4;

    for (int t = 0; t <= SEQT; ++t) {
        const bool doL0  = (t < SEQT);
        const bool doL0r = doL0 && (t > 0);
        const int  s     = t - 1;
        const bool doL1  = (t > 0);
        const bool doL1r = doL1 && (s > 0);

        // ---- L0 x-projection: independent of any flag, do before wait ----
        v4f a00 = {0.f, 0.f, 0.f, 0.f};
        v4f a01 = {0.f, 0.f, 0.f, 0.f};
        if (doL0) {
#pragma unroll
            for (int kb = 0; kb < KBI0; ++kb) {
                const float* xp = x + (m_a * SEQT + t) * 64 + kb * 32 + kh8;
                float4 f0 = ((const float4*)xp)[0];
                float4 f1 = ((const float4*)xp)[1];
                v8s a;
                a[0] = f2bf(f0.x); a[1] = f2bf(f0.y); a[2] = f2bf(f0.z); a[3] = f2bf(f0.w);
                a[4] = f2bf(f1.x); a[5] = f2bf(f1.y); a[6] = f2bf(f1.z); a[7] = f2bf(f1.w);
                a00 = __builtin_amdgcn_mfma_f32_16x16x32_bf16(a, ldsB0[(KBH + kb) * 64 + lane], a00, 0, 0, 0);
                a01 = __builtin_amdgcn_mfma_f32_16x16x32_bf16(a, ldsB0[(KBT0 + KBH + kb) * 64 + lane], a01, 0, 0, 0);
            }
        }

        // ---- wait flagL0(t-1): peers' L0 of iter t-1 done -> fA0 valid ----
        v8s fA0[16];
        if (t > 0) {
            if (wv == 0) {
                while (__hip_atomic_load(pollflagL0, __ATOMIC_RELAXED,
                                         __HIP_MEMORY_SCOPE_AGENT) < t) {
                    __builtin_amdgcn_s_sleep(2);
                }
            }
            __syncthreads();
            const __hip_bfloat16* hb0r = hbuf0 + ((t + 1) & 1) * (BATCH * HID);
            load_h16_sc1(hb0r + m_a * HID + kh8, fA0);
        }

        // ---- L0 recurrent MFMAs + cell + store + EARLY signal ----
        if (doL0) {
            if (doL0r) {
#pragma unroll
                for (int kb = 0; kb < KBH; ++kb) {
                    a00 = __builtin_amdgcn_mfma_f32_16x16x32_bf16(fA0[kb], ldsB0[kb * 64 + lane], a00, 0, 0, 0);
                    a01 = __builtin_amdgcn_mfma_f32_16x16x32_bf16(fA0[kb], ldsB0[(KBT0 + kb) * 64 + lane], a01, 0, 0, 0);
                }
            }
            float hval[4];
            cell_update(a00, a01, bi0, bf0, bg0, bo0, lowhalf, c0, hval);
            __hip_bfloat16* hb0w = hbuf0 + (t & 1) * (BATCH * HID);
            if (lowhalf) {
#pragma unroll
                for (int r = 0; r < 4; ++r) {
                    int bcell = b0 + wv * 16 + rg * 4 + r;
                    short hb = f2bf(hval[r]);
                    store_bf16_sc1(hb0w + bcell * HID + j0 + jj, (int)(unsigned short)hb);
                }
            }
            asm volatile("s_waitcnt vmcnt(0)" ::: "memory");
            __syncthreads();
            if (tid == 0) {
                __hip_atomic_store(myflagL0, t + 1, __ATOMIC_RELAXED,
                                   __HIP_MEMORY_SCOPE_AGENT);
            }
        }

        // ---- L1 step s: input MFMAs (fA0) first, then wait flagL1(t-1) ----
        if (doL1) {
            v4f a10 = {0.f, 0.f, 0.f, 0.f};
            v4f a11 = {0.f, 0.f, 0.f, 0.f};
#pragma unroll
            for (int kb = 0; kb < KBI1; ++kb) {
                a10 = __builtin_amdgcn_mfma_f32_16x16x32_bf16(fA0[kb], ldsB1[(KBH + kb) * 64 + lane], a10, 0, 0, 0);
                a11 = __builtin_amdgcn_mfma_f32_16x16x32_bf16(fA0[kb], ldsB1[(KBT1 + KBH + kb) * 64 + lane], a11, 0, 0, 0);
            }
            if (doL1r) {
                // peers signaled flagL1(t-1) at END of their iter t-1; we are
                // mid-iter t, so this wait is usually already satisfied.
                if (wv == 0) {
                    while (__hip_atomic_load(pollflagL1, __ATOMIC_RELAXED,
                                             __HIP_MEMORY_SCOPE_AGENT) < t) {
                        __builtin_amdgcn_s_sleep(2);
                    }
                }
                __syncthreads();
                v8s fA2[16];
                const __hip_bfloat16* hb1r = hbuf1 + ((s + 1) & 1) * (BATCH * HID);
                load_h16_sc1(hb1r + m_a * HID + kh8, fA2);
#pragma unroll
                for (int kb = 0; kb < KBH; ++kb) {
                    a10 = __builtin_amdgcn_mfma_f32_16x16x32_bf16(fA2[kb], ldsB1[kb * 64 + lane], a10, 0, 0, 0);
                    a11 = __builtin_amdgcn_mfma_f32_16x16x32_bf16(fA2[kb], ldsB1[(KBT1 + kb) * 64 + lane], a11, 0, 0, 0);
                }
            }
            float hval[4];
            cell_update(a10, a11, bi1, bf1, bg1, bo1, lowhalf, c1, hval);
#pragma unroll
            for (int r = 0; r < 4; ++r) hsum[r] += hval[r];
            __hip_bfloat16* hb1w = hbuf1 + (s & 1) * (BATCH * HID);
            if (lowhalf) {
#pragma unroll
                for (int r = 0; r < 4; ++r) {
                    int bcell = b0 + wv * 16 + rg * 4 + r;
                    short hb = f2bf(hval[r]);
                    store_bf16_sc1(hb1w + bcell * HID + j0 + jj, (int)(unsigned short)hb);
                }
            }
            asm volatile("s_waitcnt vmcnt(0)" ::: "memory");
            __syncthreads();
            if (tid == 0) {
                __hip_atomic_store(myflagL1, t + 1, __ATOMIC_RELAXED,
                                   __HIP_MEMORY_SCOPE_AGENT);
            }
        }
    }

    if (lowhalf) {
#pragma unroll
        for (int r = 0; r < 4; ++r) {
            int bcell = b0 + wv * 16 + rg * 4 + r;
            mean_out[bcell * HID + j0 + jj] = hsum[r] * (1.0f / (float)SEQT);
        }
    }
}

__global__ __launch_bounds__(256)
void head_kernel(const float* __restrict__ mean_h,
                 const float* __restrict__ W_sh, const float* __restrict__ b_sh,
                 const float* __restrict__ W_dir, const float* __restrict__ b_dir,
                 const float* __restrict__ W_mag, const float* __restrict__ b_mag,
                 float* __restrict__ out)
{
    __shared__ float mh[512];
    __shared__ float red[256];
    const int b = blockIdx.x;
    const int tid = threadIdx.x;

    mh[tid]       = mean_h[b * 512 + tid];
    mh[tid + 256] = mean_h[b * 512 + 256 + tid];
    __syncthreads();

    const float4* wrow = (const float4*)(W_sh + tid * 512);
    float dot = 0.f;
#pragma unroll 4
    for (int k4 = 0; k4 < 128; ++k4) {
        float4 w = wrow[k4];
        dot += w.x * mh[k4 * 4] + w.y * mh[k4 * 4 + 1]
             + w.z * mh[k4 * 4 + 2] + w.w * mh[k4 * 4 + 3];
    }
    float o = fmaxf(dot + b_sh[tid], 0.f) * 1.5f;

    red[tid] = o * W_dir[tid];
    __syncthreads();
    for (int s = 128; s > 0; s >>= 1) {
        if (tid < s) red[tid] += red[tid + s];
        __syncthreads();
    }
    if (tid == 0) out[b] = red[0] + b_dir[0];
    __syncthreads();

    red[tid] = o * W_mag[tid];
    __syncthreads();
    for (int s = 128; s > 0; s >>= 1) {
        if (tid < s) red[tid] += red[tid + s];
        __syncthreads();
    }
    if (tid == 0) out[256 + b] = red[0] + b_mag[0];
}

extern "C" void kernel_launch(void* const* d_in, const int* in_sizes, int n_in,
                              void* d_out, int out_size, void* d_ws, size_t ws_size,
                              hipStream_t stream) {
    const float* x    = (const float*)d_in[0];
    const float* Wih0 = (const float*)d_in[1];
    const float* Whh0 = (const float*)d_in[2];
    const float* b0   = (const float*)d_in[3];
    const float* Wih1 = (const float*)d_in[4];
    const float* Whh1 = (const float*)d_in[5];
    const float* b1   = (const float*)d_in[6];
    const float* Wsh  = (const float*)d_in[7];
    const float* bsh  = (const float*)d_in[8];
    const float* Wdir = (const float*)d_in[9];
    const float* bdir = (const float*)d_in[10];
    const float* Wmag = (const float*)d_in[11];
    const float* bmag = (const float*)d_in[12];

    char* ws = (char*)d_ws;
    int* flags              = (int*)(ws);
    __hip_bfloat16* hbuf0   = (__hip_bfloat16*)(ws + 8192);
    __hip_bfloat16* hbuf1   = (__hip_bfloat16*)(ws + 8192 + 524288);
    float* mean_h           = (float*)(ws + 8192 + 2 * 524288);

    hipMemsetAsync(flags, 0, 8192, stream);

    lstm_fused<<<dim3(256), dim3(256), 0, stream>>>(
        x, Wih0, Whh0, b0, Wih1, Whh1, b1,
        mean_h, hbuf0, hbuf1, flags);
    head_kernel<<<dim3(256), dim3(256), 0, stream>>>(
        mean_h, Wsh, bsh, Wdir, bdir, Wmag, bmag, (float*)d_out);
}